// Round 6
// baseline (156.923 us; speedup 1.0000x reference)
//
#include <hip/hip_runtime.h>
#include <hip/hip_bf16.h>

#define B_    2
#define SQ_   2048
#define SK_   2048
#define NH_   16
#define DH_   64
#define WIN_  256
#define NEG_  -30000.0f
#define TK    128

typedef __bf16 bf16_t;
typedef bf16_t bf16x8 __attribute__((ext_vector_type(8)));
typedef bf16_t bf16x4 __attribute__((ext_vector_type(4)));
typedef float  f32x4  __attribute__((ext_vector_type(4)));

#define KSTRIDE 72    // 64 d + 8 pad  (144 B rows, 16B-aligned)
#define VSTRIDE 136   // 128 keys + 8 pad (272 B rows, 16B-aligned)

__global__ __launch_bounds__(512, 4)
void fa_fwd(const float* __restrict__ qg, const float* __restrict__ kvg,
            float* __restrict__ outg) {
  const int tid  = threadIdx.x;
  const int wid  = tid >> 6;      // 8 waves, 16 q-rows each
  const int lane = tid & 63;
  const int quad = lane >> 4;
  const int li   = lane & 15;

  const int bid = blockIdx.x;
  const int qb  = bid >> 5;   // 16 q-blocks of 128 rows
  const int bh  = bid & 31;   // same bh -> same XCD (kv L2 locality)
  const int b   = bh >> 4;
  const int h   = bh & 15;

  const int q0b = qb * 128;
  const int q0  = q0b + wid * 16;

  __shared__ __align__(16) bf16_t sK [2][TK * KSTRIDE];   // [key][d]
  __shared__ __align__(16) bf16_t sVT[2][64 * VSTRIDE];   // [d][key, xor-swizzled]

  // ---- Q fragments, scale * log2(e) folded ----
  const float qscale = 0.125f * 1.44269504088896340736f;
  const float* qrow = qg + ((size_t)((b * SQ_ + q0 + li) * NH_ + h)) * DH_;
  bf16x8 qfrag[2];
#pragma unroll
  for (int c = 0; c < 2; ++c) {
    f32x4 a0 = *(const f32x4*)(qrow + c * 32 + quad * 8);
    f32x4 a1 = *(const f32x4*)(qrow + c * 32 + quad * 8 + 4);
#pragma unroll
    for (int i = 0; i < 4; ++i) {
      qfrag[c][i]     = (bf16_t)(a0[i] * qscale);
      qfrag[c][i + 4] = (bf16_t)(a1[i] * qscale);
    }
  }

  f32x4 oacc[4];
#pragma unroll
  for (int t = 0; t < 4; ++t) { f32x4 z = {0.f, 0.f, 0.f, 0.f}; oacc[t] = z; }
  float m = NEG_, l = 0.f;

  // block-uniform key range; always a multiple of TK given the geometry
  int klo = q0b - WIN_; if (klo < 0) klo = 0;
  int khi = q0b + 127 + WIN_ + 1; if (khi > SK_) khi = SK_;

  const float* kbase = kvg + (size_t)b * SK_ * 2 * NH_ * DH_ + (size_t)h * DH_;
  const float* vbase = kbase + NH_ * DH_;
  const size_t krow = 2 * NH_ * DH_;

  // K staging: thread -> (row, 16-col segment); V staging: thread -> (d=lane, 16-key group=wid)
  const int skey = tid >> 2;          // 0..127
  const int sd0  = (tid & 3) * 16;    // 0,16,32,48
  const int vg   = (lane >> 3) & 7;   // xor swizzle for this d-row

  f32x4 ka[4]; float vv[16];

  auto load_tile = [&](int kt) {
    const float* kr = kbase + (size_t)(kt + skey) * krow + sd0;
#pragma unroll
    for (int i = 0; i < 4; ++i) ka[i] = *(const f32x4*)(kr + 4 * i);
    const float* vr = vbase + (size_t)(kt + wid * 16) * krow + lane;
#pragma unroll
    for (int j = 0; j < 16; ++j) vv[j] = vr[(size_t)j * krow];
  };
  auto stage = [&](int bw) {
    bf16x8 u0, u1;
#pragma unroll
    for (int i = 0; i < 4; ++i) {
      u0[i] = (bf16_t)ka[0][i]; u0[i + 4] = (bf16_t)ka[1][i];
      u1[i] = (bf16_t)ka[2][i]; u1[i + 4] = (bf16_t)ka[3][i];
    }
    *(bf16x8*)&sK[bw][skey * KSTRIDE + sd0]     = u0;
    *(bf16x8*)&sK[bw][skey * KSTRIDE + sd0 + 8] = u1;
    bf16x8 w0, w1;
#pragma unroll
    for (int j = 0; j < 8; ++j) { w0[j] = (bf16_t)vv[j]; w1[j] = (bf16_t)vv[8 + j]; }
    *(bf16x8*)&sVT[bw][lane * VSTRIDE + (((2 * wid)     ^ vg) << 3)] = w0;
    *(bf16x8*)&sVT[bw][lane * VSTRIDE + (((2 * wid + 1) ^ vg) << 3)] = w1;
  };

  load_tile(klo);
  stage(0);
  __syncthreads();

  const int wlo = q0 - WIN_;        // union-over-rows valid key range
  const int whi = q0 + 15 + WIN_;

  int buf = 0;
  for (int kk = klo; kk < khi; kk += TK) {
    const bool nxt = (kk + TK < khi);
    if (nxt) load_tile(kk + TK);    // global loads in flight across compute

    // two 64-key halves (keeps VGPR pressure at round-5 levels)
#pragma unroll
    for (int hf = 0; hf < 2; ++hf) {
      const int kb = kk + hf * 64;
      if (kb + 63 >= wlo && kb <= whi) {     // wave-uniform half-skip
        // ---- S^T = K . Q^T ----
        f32x4 sc[4];
#pragma unroll
        for (int s = 0; s < 4; ++s) {
          const int k0 = kb + s * 16;
          if (k0 + 15 >= wlo && k0 <= whi) { // wave-uniform subtile skip
            const int row = (hf * 64 + s * 16 + li) * KSTRIDE;
            bf16x8 kf0 = *(const bf16x8*)&sK[buf][row + quad * 8];
            bf16x8 kf1 = *(const bf16x8*)&sK[buf][row + 32 + quad * 8];
            f32x4 acc = {0.f, 0.f, 0.f, 0.f};
            acc = __builtin_amdgcn_mfma_f32_16x16x32_bf16(kf0, qfrag[0], acc, 0, 0, 0);
            acc = __builtin_amdgcn_mfma_f32_16x16x32_bf16(kf1, qfrag[1], acc, 0, 0, 0);
            sc[s] = acc;
          } else {
            f32x4 z = {NEG_, NEG_, NEG_, NEG_}; sc[s] = z;
          }
        }
        // boundary mask only when the half isn't fully inside
        if (kb < q0 - 241 || kb > q0 + 193) {
          const int qa = q0 + li;
#pragma unroll
          for (int s = 0; s < 4; ++s)
#pragma unroll
            for (int r = 0; r < 4; ++r) {
              int key = kb + s * 16 + quad * 4 + r;
              unsigned dd = (unsigned)(key - qa + WIN_);
              if (dd > 2u * WIN_) sc[s][r] = NEG_;
            }
        }
        // ---- online softmax (state per q-col = li) ----
        float tmax = NEG_;
#pragma unroll
        for (int s = 0; s < 4; ++s)
          tmax = fmaxf(tmax, fmaxf(fmaxf(sc[s][0], sc[s][1]), fmaxf(sc[s][2], sc[s][3])));
        tmax = fmaxf(tmax, __shfl_xor(tmax, 16));
        tmax = fmaxf(tmax, __shfl_xor(tmax, 32));
        float mnew  = fmaxf(m, tmax);
        float alpha = exp2f(m - mnew);
        float psum = 0.f;
        bf16x8 pa[2];   // A-fragments for PV under the sigma key-permutation
#pragma unroll
        for (int s = 0; s < 4; ++s)
#pragma unroll
          for (int r = 0; r < 4; ++r) {
            float p = exp2f(sc[s][r] - mnew);
            psum += p;
            pa[s >> 1][(s & 1) * 4 + r] = (bf16_t)p;
          }
        psum += __shfl_xor(psum, 16);
        psum += __shfl_xor(psum, 32);
        l = l * alpha + psum;
        m = mnew;
        // ---- rescale O (alpha per q-row = quad*4+r) ----
        float al[4];
#pragma unroll
        for (int r = 0; r < 4; ++r) al[r] = __shfl(alpha, quad * 4 + r);
#pragma unroll
        for (int t = 0; t < 4; ++t) {
          oacc[t][0] *= al[0]; oacc[t][1] *= al[1];
          oacc[t][2] *= al[2]; oacc[t][3] *= al[3];
        }
        // ---- O += P . V ; B-frag reads match sigma: two b64 per (kc,t) ----
#pragma unroll
        for (int kc = 0; kc < 2; ++kc) {
          const int c0 = kb + kc * 32;
          if (c0 + 31 >= wlo && c0 <= whi) {
            const int c8lo = hf * 8 + 4 * kc + (quad >> 1);      // key128>>3 groups
#pragma unroll
            for (int t = 0; t < 4; ++t) {
              const int d = 16 * t + li;
              const int g = (d >> 3) & 7;
              const int rowo = d * VSTRIDE + (quad & 1) * 4;
              bf16x4 lo = *(const bf16x4*)&sVT[buf][rowo + ((c8lo       ^ g) << 3)];
              bf16x4 hi = *(const bf16x4*)&sVT[buf][rowo + (((c8lo + 2) ^ g) << 3)];
              bf16x8 vf = {lo[0], lo[1], lo[2], lo[3], hi[0], hi[1], hi[2], hi[3]};
              oacc[t] = __builtin_amdgcn_mfma_f32_16x16x32_bf16(pa[kc], vf, oacc[t], 0, 0, 0);
            }
          }
        }
      }
    }

    if (nxt) stage(buf ^ 1);   // buf^1 reads finished before last barrier
    __syncthreads();           // single barrier per 128 keys
    buf ^= 1;
  }

  // ---- epilogue ----
  float rl[4];
#pragma unroll
  for (int r = 0; r < 4; ++r) {
    float lv = __shfl(l, quad * 4 + r);
    rl[r] = 1.0f / lv;
  }
  float* orow = outg + ((size_t)((b * SQ_ + q0) * NH_ + h)) * DH_;
#pragma unroll
  for (int t = 0; t < 4; ++t)
#pragma unroll
    for (int r = 0; r < 4; ++r)
      orow[(size_t)(quad * 4 + r) * (NH_ * DH_) + 16 * t + li] = oacc[t][r] * rl[r];
}

extern "C" void kernel_launch(void* const* d_in, const int* in_sizes, int n_in,
                              void* d_out, int out_size, void* d_ws, size_t ws_size,
                              hipStream_t stream) {
  (void)in_sizes; (void)n_in; (void)out_size; (void)d_ws; (void)ws_size;
  const float* q  = (const float*)d_in[0];
  const float* kv = (const float*)d_in[1];
  float* out = (float*)d_out;
  dim3 grid(B_ * NH_ * (SQ_ / 128));  // 512 blocks x 8 waves
  fa_fwd<<<grid, 512, 0, stream>>>(q, kv, out);
}

// Round 7
// 116.141 us; speedup vs baseline: 1.3511x; 1.3511x over previous
//
#include <hip/hip_runtime.h>
#include <hip/hip_bf16.h>

#define B_    2
#define SQ_   2048
#define SK_   2048
#define NH_   16
#define DH_   64
#define WIN_  256
#define NEG_  -30000.0f

typedef __bf16 bf16_t;
typedef bf16_t bf16x8 __attribute__((ext_vector_type(8)));
typedef bf16_t bf16x4 __attribute__((ext_vector_type(4)));
typedef float  f32x4  __attribute__((ext_vector_type(4)));

#define KSTRIDE 72    // 64 d + 8 pad (144 B rows, 16B-aligned)
#define VSTRIDE 72    // 64 keys + 8 pad

__global__ __launch_bounds__(512, 4)
void fa_fwd(const float* __restrict__ qg, const float* __restrict__ kvg,
            float* __restrict__ outg) {
  const int tid  = threadIdx.x;
  const int wid  = tid >> 6;      // 8 waves, 16 q-rows each
  const int lane = tid & 63;
  const int quad = lane >> 4;
  const int li   = lane & 15;

  const int bid = blockIdx.x;
  const int qb  = bid >> 5;   // 16 q-blocks of 128 rows
  const int bh  = bid & 31;   // same bh -> same XCD (kv L2 locality)
  const int b   = bh >> 4;
  const int h   = bh & 15;

  const int q0b = qb * 128;
  const int q0  = q0b + wid * 16;

  __shared__ __align__(16) bf16_t sK [2][64 * KSTRIDE];   // [key][d]
  __shared__ __align__(16) bf16_t sVT[2][64 * VSTRIDE];   // [d][key-octet, xor-swizzled]

  // ---- Q fragments, scale * log2(e) folded ----
  const float qscale = 0.125f * 1.44269504088896340736f;
  const float* qrow = qg + ((size_t)((b * SQ_ + q0 + li) * NH_ + h)) * DH_;
  bf16x8 qfrag[2];
#pragma unroll
  for (int c = 0; c < 2; ++c) {
    f32x4 a0 = *(const f32x4*)(qrow + c * 32 + quad * 8);
    f32x4 a1 = *(const f32x4*)(qrow + c * 32 + quad * 8 + 4);
#pragma unroll
    for (int i = 0; i < 4; ++i) {
      qfrag[c][i]     = (bf16_t)(a0[i] * qscale);
      qfrag[c][i + 4] = (bf16_t)(a1[i] * qscale);
    }
  }

  f32x4 oacc[4];
#pragma unroll
  for (int t = 0; t < 4; ++t) { f32x4 z = {0.f, 0.f, 0.f, 0.f}; oacc[t] = z; }
  float m = NEG_, l = 0.f;

  // block-uniform 64-aligned key range
  int klo = q0b - WIN_; if (klo < 0) klo = 0;
  int khi = q0b + 127 + WIN_ + 1; if (khi > SK_) khi = SK_;

  const float* kbase = kvg + (size_t)b * SK_ * 2 * NH_ * DH_ + (size_t)h * DH_;
  const float* vbase = kbase + NH_ * DH_;
  const size_t krow = 2 * NH_ * DH_;

  // K staging: 512 threads cover 64 keys x 64 d (8 floats each)
  const int skey = tid >> 3;        // 0..63
  const int sd0  = (tid & 7) * 8;   // 0,8,...,56
  // V staging: thread -> (d = lane, key-octet = wid); transpose happens on the
  // global side (coalesced strided scalar loads), LDS store is one b128
  const int vg   = (lane >> 3) & 7;             // xor swizzle for this d-row
  const int vcol = ((wid ^ vg) << 3);

  f32x4 ka[2]; float vv[8];

  auto load_tile = [&](int kt) {
    const float* kr = kbase + (size_t)(kt + skey) * krow + sd0;
    ka[0] = *(const f32x4*)kr;  ka[1] = *(const f32x4*)(kr + 4);
    const float* vr = vbase + (size_t)(kt + wid * 8) * krow + lane;
#pragma unroll
    for (int j = 0; j < 8; ++j) vv[j] = vr[(size_t)j * krow];
  };
  auto stage = [&](int bw) {
    bf16x8 u;
#pragma unroll
    for (int i = 0; i < 4; ++i) { u[i] = (bf16_t)ka[0][i]; u[i + 4] = (bf16_t)ka[1][i]; }
    *(bf16x8*)&sK[bw][skey * KSTRIDE + sd0] = u;
    bf16x8 w;
#pragma unroll
    for (int j = 0; j < 8; ++j) w[j] = (bf16_t)vv[j];
    *(bf16x8*)&sVT[bw][lane * VSTRIDE + vcol] = w;
  };

  load_tile(klo);
  stage(0);
  __syncthreads();

  int buf = 0;
  for (int kk = klo; kk < khi; kk += 64) {
    const bool nxt = (kk + 64 < khi);
    if (nxt) load_tile(kk + 64);    // global loads in flight across compute

    if (kk + 63 >= q0 - WIN_ && kk <= q0 + 15 + WIN_) {   // wave-uniform skip
      // ---- S^T = K . Q^T : 4 key subtiles, D=64 as two K=32 chunks ----
      f32x4 sc[4];
#pragma unroll
      for (int s = 0; s < 4; ++s) {
        const int row = (s * 16 + li) * KSTRIDE;
        bf16x8 kf0 = *(const bf16x8*)&sK[buf][row + quad * 8];
        bf16x8 kf1 = *(const bf16x8*)&sK[buf][row + 32 + quad * 8];
        f32x4 acc = {0.f, 0.f, 0.f, 0.f};
        acc = __builtin_amdgcn_mfma_f32_16x16x32_bf16(kf0, qfrag[0], acc, 0, 0, 0);
        acc = __builtin_amdgcn_mfma_f32_16x16x32_bf16(kf1, qfrag[1], acc, 0, 0, 0);
        sc[s] = acc;
      }
      // ---- window mask only on boundary tiles (wave-uniform) ----
      if (kk < q0 - 241 || kk > q0 + 193) {
        const int qa = q0 + li;
#pragma unroll
        for (int s = 0; s < 4; ++s)
#pragma unroll
          for (int r = 0; r < 4; ++r) {
            int key = kk + s * 16 + quad * 4 + r;
            unsigned dd = (unsigned)(key - qa + WIN_);
            if (dd > 2u * WIN_) sc[s][r] = NEG_;
          }
      }
      // ---- online softmax (state per q-col = li) ----
      float tmax = NEG_;
#pragma unroll
      for (int s = 0; s < 4; ++s)
        tmax = fmaxf(tmax, fmaxf(fmaxf(sc[s][0], sc[s][1]), fmaxf(sc[s][2], sc[s][3])));
      tmax = fmaxf(tmax, __shfl_xor(tmax, 16));
      tmax = fmaxf(tmax, __shfl_xor(tmax, 32));
      float mnew  = fmaxf(m, tmax);
      float alpha = exp2f(m - mnew);
      float psum = 0.f;
      bf16x8 pa[2];   // P as PV A-fragments under the sigma key-permutation
#pragma unroll
      for (int s = 0; s < 4; ++s)
#pragma unroll
        for (int r = 0; r < 4; ++r) {
          float p = exp2f(sc[s][r] - mnew);
          psum += p;
          pa[s >> 1][(s & 1) * 4 + r] = (bf16_t)p;
        }
      psum += __shfl_xor(psum, 16);
      psum += __shfl_xor(psum, 32);
      l = l * alpha + psum;
      m = mnew;
      // ---- rescale O (alpha per q-row = quad*4+r) ----
      float al[4];
#pragma unroll
      for (int r = 0; r < 4; ++r) al[r] = __shfl(alpha, quad * 4 + r);
#pragma unroll
      for (int t = 0; t < 4; ++t) {
        oacc[t][0] *= al[0]; oacc[t][1] *= al[1];
        oacc[t][2] *= al[2]; oacc[t][3] *= al[3];
      }
      // ---- O += P . V ; B-frag reads match sigma: two b64 per (kc,t) ----
#pragma unroll
      for (int kc = 0; kc < 2; ++kc) {
        const int olo = kc * 4 + (quad >> 1);   // key-octet of j=0..3
#pragma unroll
        for (int t = 0; t < 4; ++t) {
          const int d = 16 * t + li;
          const int g = (d >> 3) & 7;
          const int rowo = d * VSTRIDE + (quad & 1) * 4;
          bf16x4 lo = *(const bf16x4*)&sVT[buf][rowo + ((olo       ^ g) << 3)];
          bf16x4 hi = *(const bf16x4*)&sVT[buf][rowo + (((olo + 2) ^ g) << 3)];
          bf16x8 vf = {lo[0], lo[1], lo[2], lo[3], hi[0], hi[1], hi[2], hi[3]};
          oacc[t] = __builtin_amdgcn_mfma_f32_16x16x32_bf16(pa[kc], vf, oacc[t], 0, 0, 0);
        }
      }
    }

    if (nxt) stage(buf ^ 1);   // buf^1 reads all finished before last barrier
    __syncthreads();           // single barrier per iteration
    buf ^= 1;
  }

  // ---- epilogue ----
  float rl[4];
#pragma unroll
  for (int r = 0; r < 4; ++r) {
    float lv = __shfl(l, quad * 4 + r);
    rl[r] = 1.0f / lv;
  }
  float* orow = outg + ((size_t)((b * SQ_ + q0) * NH_ + h)) * DH_;
#pragma unroll
  for (int t = 0; t < 4; ++t)
#pragma unroll
    for (int r = 0; r < 4; ++r)
      orow[(size_t)(quad * 4 + r) * (NH_ * DH_) + 16 * t + li] = oacc[t][r] * rl[r];
}

extern "C" void kernel_launch(void* const* d_in, const int* in_sizes, int n_in,
                              void* d_out, int out_size, void* d_ws, size_t ws_size,
                              hipStream_t stream) {
  (void)in_sizes; (void)n_in; (void)out_size; (void)d_ws; (void)ws_size;
  const float* q  = (const float*)d_in[0];
  const float* kv = (const float*)d_in[1];
  float* out = (float*)d_out;
  dim3 grid(B_ * NH_ * (SQ_ / 128));  // 512 blocks x 8 waves
  fa_fwd<<<grid, 512, 0, stream>>>(q, kv, out);
}

// Round 8
// 112.104 us; speedup vs baseline: 1.3998x; 1.0360x over previous
//
#include <hip/hip_runtime.h>
#include <hip/hip_bf16.h>

#define B_    2
#define SQ_   2048
#define SK_   2048
#define NH_   16
#define DH_   64
#define WIN_  256
#define NEG_  -30000.0f

typedef __bf16 bf16_t;
typedef bf16_t bf16x8 __attribute__((ext_vector_type(8)));
typedef bf16_t bf16x4 __attribute__((ext_vector_type(4)));
typedef float  f32x4  __attribute__((ext_vector_type(4)));

#define KSTRIDE 72    // 64 d + 8 pad (144 B rows, 16B-aligned)
#define VSTRIDE 72    // 64 keys + 8 pad

__global__ __launch_bounds__(256, 3)
void fa_fwd(const float* __restrict__ qg, const float* __restrict__ kvg,
            float* __restrict__ outg) {
  const int tid  = threadIdx.x;
  const int wid  = tid >> 6;      // 4 waves, 32 q-rows each
  const int lane = tid & 63;
  const int quad = lane >> 4;
  const int li   = lane & 15;

  const int bid = blockIdx.x;
  const int qb  = bid >> 5;   // 16 q-blocks of 128 rows
  const int bh  = bid & 31;   // same bh -> same XCD (kv L2 locality)
  const int b   = bh >> 4;
  const int h   = bh & 15;

  const int q0b = qb * 128;
  const int q0  = q0b + wid * 32;   // wave's 32 q-rows = 2 tiles of 16

  __shared__ __align__(16) bf16_t sK [2][64 * KSTRIDE];   // [key][d]
  __shared__ __align__(16) bf16_t sVT[2][64 * VSTRIDE];   // [d][key-octet, xor-swizzled]

  // ---- Q fragments for both q-tiles, scale * log2(e) folded ----
  const float qscale = 0.125f * 1.44269504088896340736f;
  bf16x8 qfrag[2][2];
#pragma unroll
  for (int qt = 0; qt < 2; ++qt) {
    const float* qrow = qg + ((size_t)((b * SQ_ + q0 + qt * 16 + li) * NH_ + h)) * DH_;
#pragma unroll
    for (int c = 0; c < 2; ++c) {
      f32x4 a0 = *(const f32x4*)(qrow + c * 32 + quad * 8);
      f32x4 a1 = *(const f32x4*)(qrow + c * 32 + quad * 8 + 4);
#pragma unroll
      for (int i = 0; i < 4; ++i) {
        qfrag[qt][c][i]     = (bf16_t)(a0[i] * qscale);
        qfrag[qt][c][i + 4] = (bf16_t)(a1[i] * qscale);
      }
    }
  }

  f32x4 oacc[2][4];
#pragma unroll
  for (int qt = 0; qt < 2; ++qt)
#pragma unroll
    for (int t = 0; t < 4; ++t) { f32x4 z = {0.f, 0.f, 0.f, 0.f}; oacc[qt][t] = z; }
  float m[2] = {NEG_, NEG_}, l[2] = {0.f, 0.f};

  // block-uniform 64-aligned key range
  int klo = q0b - WIN_; if (klo < 0) klo = 0;
  int khi = q0b + 127 + WIN_ + 1; if (khi > SK_) khi = SK_;

  const float* kbase = kvg + (size_t)b * SK_ * 2 * NH_ * DH_ + (size_t)h * DH_;
  const float* vbase = kbase + NH_ * DH_;
  const size_t krow = 2 * NH_ * DH_;

  // K staging: 256 threads cover 64 keys x 64 d, 16 floats (2 b128) each
  const int skey = tid >> 2;        // 0..63
  const int sd0  = (tid & 3) * 16;  // 0,16,32,48
  // V staging: thread -> (d = lane, key-octets 2*wid, 2*wid+1); transpose on the
  // global side (coalesced scalar loads), LDS stores are b128, xor-swizzled
  const int vg   = (lane >> 3) & 7;

  bf16x8 kpre[2], vpre[2];   // prefetch held as bf16 (16 VGPR total)

  auto load_tile = [&](int kt) {
    const float* kr = kbase + (size_t)(kt + skey) * krow + sd0;
    f32x4 a0 = *(const f32x4*)kr,      a1 = *(const f32x4*)(kr + 4);
    f32x4 a2 = *(const f32x4*)(kr + 8), a3 = *(const f32x4*)(kr + 12);
#pragma unroll
    for (int i = 0; i < 4; ++i) {
      kpre[0][i] = (bf16_t)a0[i]; kpre[0][i + 4] = (bf16_t)a1[i];
      kpre[1][i] = (bf16_t)a2[i]; kpre[1][i + 4] = (bf16_t)a3[i];
    }
    const float* vr = vbase + (size_t)(kt + wid * 16) * krow + lane;
#pragma unroll
    for (int o = 0; o < 2; ++o)
#pragma unroll
      for (int j = 0; j < 8; ++j)
        vpre[o][j] = (bf16_t)vr[(size_t)(o * 8 + j) * krow];
  };
  auto stage = [&](bf16_t* sKb, bf16_t* sVb) {
    *(bf16x8*)&sKb[skey * KSTRIDE + sd0]     = kpre[0];
    *(bf16x8*)&sKb[skey * KSTRIDE + sd0 + 8] = kpre[1];
#pragma unroll
    for (int o = 0; o < 2; ++o)
      *(bf16x8*)&sVb[lane * VSTRIDE + (((2 * wid + o) ^ vg) << 3)] = vpre[o];
  };

  bf16_t *sKc = sK[0], *sVc = sVT[0], *sKn = sK[1], *sVn = sVT[1];

  load_tile(klo);
  stage(sKc, sVc);
  __syncthreads();

  for (int kk = klo; kk < khi; kk += 64) {
    const bool nxt = (kk + 64 < khi);
    if (nxt) load_tile(kk + 64);    // global loads in flight across compute

    if (kk + 63 >= q0 - WIN_ && kk <= q0 + 31 + WIN_) {   // wave-uniform skip
      // ---- S^T = K . Q^T : kf shared across both q-tiles ----
      f32x4 sc[2][4];
#pragma unroll
      for (int s = 0; s < 4; ++s) {
        const int row = (s * 16 + li) * KSTRIDE;
        bf16x8 kf0 = *(const bf16x8*)&sKc[row + quad * 8];
        bf16x8 kf1 = *(const bf16x8*)&sKc[row + 32 + quad * 8];
#pragma unroll
        for (int qt = 0; qt < 2; ++qt) {
          f32x4 acc = {0.f, 0.f, 0.f, 0.f};
          acc = __builtin_amdgcn_mfma_f32_16x16x32_bf16(kf0, qfrag[qt][0], acc, 0, 0, 0);
          acc = __builtin_amdgcn_mfma_f32_16x16x32_bf16(kf1, qfrag[qt][1], acc, 0, 0, 0);
          sc[qt][s] = acc;
        }
      }
      // ---- per-q-tile: mask (boundary only) + online softmax + P pack ----
      float alpha[2];
      bf16x8 pa[2][2];
#pragma unroll
      for (int qt = 0; qt < 2; ++qt) {
        const int t0 = q0 + qt * 16;
        if (kk < t0 - 241 || kk > t0 + 193) {
          const int qa = t0 + li;
#pragma unroll
          for (int s = 0; s < 4; ++s)
#pragma unroll
            for (int r = 0; r < 4; ++r) {
              int key = kk + s * 16 + quad * 4 + r;
              unsigned dd = (unsigned)(key - qa + WIN_);
              if (dd > 2u * WIN_) sc[qt][s][r] = NEG_;
            }
        }
        float tmax = NEG_;
#pragma unroll
        for (int s = 0; s < 4; ++s)
          tmax = fmaxf(tmax, fmaxf(fmaxf(sc[qt][s][0], sc[qt][s][1]),
                                   fmaxf(sc[qt][s][2], sc[qt][s][3])));
        tmax = fmaxf(tmax, __shfl_xor(tmax, 16));
        tmax = fmaxf(tmax, __shfl_xor(tmax, 32));
        float mnew = fmaxf(m[qt], tmax);
        alpha[qt] = __builtin_amdgcn_exp2f(m[qt] - mnew);
        float psum = 0.f;
#pragma unroll
        for (int s = 0; s < 4; ++s)
#pragma unroll
          for (int r = 0; r < 4; ++r) {
            float p = __builtin_amdgcn_exp2f(sc[qt][s][r] - mnew);
            psum += p;
            pa[qt][s >> 1][(s & 1) * 4 + r] = (bf16_t)p;  // sigma-permuted A-frag
          }
        psum += __shfl_xor(psum, 16);
        psum += __shfl_xor(psum, 32);
        l[qt] = l[qt] * alpha[qt] + psum;
        m[qt] = mnew;
        // rescale O (alpha per q-row = quad*4+r)
        float al[4];
#pragma unroll
        for (int r = 0; r < 4; ++r) al[r] = __shfl(alpha[qt], quad * 4 + r);
#pragma unroll
        for (int t = 0; t < 4; ++t) {
          oacc[qt][t][0] *= al[0]; oacc[qt][t][1] *= al[1];
          oacc[qt][t][2] *= al[2]; oacc[qt][t][3] *= al[3];
        }
      }
      // ---- O += P . V ; vf shared across both q-tiles (sigma-matched b64 pairs) ----
#pragma unroll
      for (int kc = 0; kc < 2; ++kc) {
        const int olo = kc * 4 + (quad >> 1);
#pragma unroll
        for (int t = 0; t < 4; ++t) {
          const int d = 16 * t + li;
          const int g = (d >> 3) & 7;
          const int rowo = d * VSTRIDE + (quad & 1) * 4;
          bf16x4 lo = *(const bf16x4*)&sVc[rowo + ((olo       ^ g) << 3)];
          bf16x4 hi = *(const bf16x4*)&sVc[rowo + (((olo + 2) ^ g) << 3)];
          bf16x8 vf = {lo[0], lo[1], lo[2], lo[3], hi[0], hi[1], hi[2], hi[3]};
          oacc[0][t] = __builtin_amdgcn_mfma_f32_16x16x32_bf16(pa[0][kc], vf, oacc[0][t], 0, 0, 0);
          oacc[1][t] = __builtin_amdgcn_mfma_f32_16x16x32_bf16(pa[1][kc], vf, oacc[1][t], 0, 0, 0);
        }
      }
    }

    if (nxt) stage(sKn, sVn);   // next-buffer reads all finished before last barrier
    __syncthreads();            // single barrier per iteration
    bf16_t* t0 = sKc; sKc = sKn; sKn = t0;
    bf16_t* t1 = sVc; sVc = sVn; sVn = t1;
  }

  // ---- epilogue ----
#pragma unroll
  for (int qt = 0; qt < 2; ++qt) {
    float rl[4];
#pragma unroll
    for (int r = 0; r < 4; ++r) {
      float lv = __shfl(l[qt], quad * 4 + r);
      rl[r] = 1.0f / lv;
    }
    float* orow = outg + ((size_t)((b * SQ_ + q0 + qt * 16) * NH_ + h)) * DH_;
#pragma unroll
    for (int t = 0; t < 4; ++t)
#pragma unroll
      for (int r = 0; r < 4; ++r)
        orow[(size_t)(quad * 4 + r) * (NH_ * DH_) + 16 * t + li] = oacc[qt][t][r] * rl[r];
  }
}

extern "C" void kernel_launch(void* const* d_in, const int* in_sizes, int n_in,
                              void* d_out, int out_size, void* d_ws, size_t ws_size,
                              hipStream_t stream) {
  (void)in_sizes; (void)n_in; (void)out_size; (void)d_ws; (void)ws_size;
  const float* q  = (const float*)d_in[0];
  const float* kv = (const float*)d_in[1];
  float* out = (float*)d_out;
  dim3 grid(B_ * NH_ * (SQ_ / 128));  // 512 blocks x 4 waves
  fa_fwd<<<grid, 256, 0, stream>>>(q, kv, out);
}